// Round 16
// baseline (3001.673 us; speedup 1.0000x reference)
//
#include <hip/hip_runtime.h>
#include <hip/hip_fp16.h>
#include <stdint.h>

#define S_LEN 1024
#define BATCH 64
#define HID   512
#define VOC   256

typedef _Float16 h2v __attribute__((ext_vector_type(2)));
typedef _Float16 h8v __attribute__((ext_vector_type(8)));
typedef float    f4v __attribute__((ext_vector_type(4)));

// ---------------- prep kernels ----------------
// Fragment-packed W_hh for mfma_f32_16x16x32_f16 B-operand.
// frag f = nt*16 + kc (nt in [0,32): 16 output cols; kc in [0,16): 32 k).
// lane l, reg r: uint32 = pack(W[k][j], W[k+1][j]), k = kc*32 + (l>>4)*8 + 2r,
// j = nt*16 + (l&15).  wf uint32 index = f*256 + l*4 + r.
__global__ void prep_wfrag(const float* __restrict__ whh, uint32_t* __restrict__ wf) {
  int idx = blockIdx.x * blockDim.x + threadIdx.x;  // 131072
  int f = idx >> 8;
  int rem = idx & 255;
  int l = rem >> 2;
  int r = rem & 3;
  int nt = f >> 4;
  int kc = f & 15;
  int k = kc * 32 + (l >> 4) * 8 + 2 * r;
  int j = nt * 16 + (l & 15);
  h2v p;
  p.x = (_Float16)whh[k * HID + j];
  p.y = (_Float16)whh[(k + 1) * HID + j];
  wf[idx] = __builtin_bit_cast(uint32_t, p);
}

// W_hyT[v*HID + k] = fp16 W_hy[k][v]
__global__ void prep_why(const float* __restrict__ why, _Float16* __restrict__ wt) {
  int idx = blockIdx.x * blockDim.x + threadIdx.x;  // 131072
  int v = idx >> 9;
  int k = idx & 511;
  wt[idx] = (_Float16)why[k * VOC + v];
}

// ---------------- phase 1: recurrence via intrinsic MFMA ----------------
// 64 blocks (one chain) -> 1 block/CU on 64 of 256 CUs; 512 threads = 8 waves.
// Wave w owns output cols [64w, 64w+64) = tiles nt = 4w..4w+3.
//   nt0..nt2: B-frags in plain SSA arrays (192 regs/thread; compiler assigns
//             AGPR/VGPR itself -- budget 256, usage ~240, no pressure/no remat)
//   nt3:      B-frags streamed from wf each step (L2-hot, 128 KB/step/CU)
// A operand = h chunk replicated across rows: all lanes of a 16-lane group read
// the same 16 B of h2s -> all 16 D rows equal y; lane l's col = w*64 + l.
// Per-step LDS ops: 16 broadcast b128 h-reads/thread (weights bypass LDS).
__global__ __launch_bounds__(512, 2) void rnn_phase1(
    const int* __restrict__ x, const float* __restrict__ wih,
    const h8v* __restrict__ wf, const float* __restrict__ bh,
    __half* __restrict__ hbuf) {
  __shared__ __align__(16) uint32_t h2s[HID / 2];  // h fp16[512], 1 KB
  __shared__ int xtok[S_LEN];                      // 4 KB

  const int b   = blockIdx.x;
  const int tid = threadIdx.x;
  const int w   = tid >> 6;
  const int l   = tid & 63;
  const int g   = (tid >> 4) & 3;  // lane 16-group == l>>4

  // ---- one-time: 3 register-resident tiles (48 frags = 192 regs/thread)
  h8v wa0[16], wa1[16], wa2[16];
#pragma unroll
  for (int kc = 0; kc < 16; ++kc) {
    wa0[kc] = wf[((4 * w + 0) * 16 + kc) * 64 + l];
    wa1[kc] = wf[((4 * w + 1) * 16 + kc) * 64 + l];
    wa2[kc] = wf[((4 * w + 2) * 16 + kc) * 64 + l];
  }

  xtok[tid]       = x[b * S_LEN + tid];
  xtok[tid + 512] = x[b * S_LEN + tid + 512];
  if (tid < HID / 2) h2s[tid] = 0u;  // h0 = 0
  const float bh_r = bh[tid];
  const h8v* gbase = wf + ((4 * w + 3) * 16) * 64 + l;  // streamed tile base
  __syncthreads();

  for (int t = 0; t < S_LEN; ++t) {
    const int tok = xtok[t];
    const float xe = wih[tok * HID + tid];  // early issue; used in epilogue

    f4v acc0 = {0.f, 0.f, 0.f, 0.f};
    f4v acc1 = {0.f, 0.f, 0.f, 0.f};
    f4v acc2 = {0.f, 0.f, 0.f, 0.f};
    f4v acc3 = {0.f, 0.f, 0.f, 0.f};

#pragma unroll
    for (int kc = 0; kc < 16; ++kc) {
      // A = h[kc*32 + g*8 .. +8] (16 B broadcast within each 16-lane group)
      const h8v af = *((const h8v*)((const char*)h2s + kc * 64 + g * 16));
      const h8v gf = gbase[kc * 64];  // streamed tile frag (L2)
      acc0 = __builtin_amdgcn_mfma_f32_16x16x32_f16(af, wa0[kc], acc0, 0, 0, 0);
      acc1 = __builtin_amdgcn_mfma_f32_16x16x32_f16(af, wa1[kc], acc1, 0, 0, 0);
      acc2 = __builtin_amdgcn_mfma_f32_16x16x32_f16(af, wa2[kc], acc2, 0, 0, 0);
      acc3 = __builtin_amdgcn_mfma_f32_16x16x32_f16(af, gf,      acc3, 0, 0, 0);
    }

    __syncthreads();  // B1: all h2s reads of step t complete before overwrite

    {
      // lane l owns col n = w*64 + l: group g picks tile, l&15 the col within.
      // D rows all equal (A replicated) -> element 0 is y[col].
      const float y = (g == 0) ? acc0[0] : (g == 1) ? acc1[0]
                    : (g == 2) ? acc2[0] : acc3[0];
      float s = y + xe + bh_r;
      const float e = __builtin_amdgcn_exp2f(s * 2.885390081777927f);  // e^(2s)
      const float h = 1.0f - 2.0f * __builtin_amdgcn_rcpf(e + 1.0f);
      const __half hh = __float2half(h);
      ((__half*)h2s)[tid] = hh;                          // recurrent state
      hbuf[(size_t)(t * BATCH + b) * HID + tid] = hh;    // history for phase 2
    }
    __syncthreads();  // B2: new h visible before next step's reads
  }
}

// ---------------- phase 2: y = h @ W_hy + b_y (fp16 MFMA, in-place over d_out) ----
__global__ __launch_bounds__(256, 1) void rnn_phase2(
    void* __restrict__ out_, const _Float16* __restrict__ wt,
    const float* __restrict__ by) {
  const int tid = threadIdx.x;
  const int w = tid >> 6;
  const int l = tid & 63;
  const int la = l & 15;
  const int lb = l >> 4;
  const int rowbase = blockIdx.x * 64 + w * 16;

  const _Float16* hb = (const _Float16*)out_;
  float* out = (float*)out_;

  h8v a[16];
  const _Float16* arow = hb + (size_t)(rowbase + la) * HID + lb * 8;
#pragma unroll
  for (int kk = 0; kk < 16; ++kk)
    a[kk] = *((const h8v*)(arow + kk * 32));

#pragma unroll 1
  for (int cb = 0; cb < 16; ++cb) {
    f4v acc = {0.f, 0.f, 0.f, 0.f};
    const _Float16* brow = wt + (size_t)(cb * 16 + la) * HID + lb * 8;
#pragma unroll
    for (int kk = 0; kk < 16; ++kk) {
      const h8v bf = *((const h8v*)(brow + kk * 32));
      acc = __builtin_amdgcn_mfma_f32_16x16x32_f16(a[kk], bf, acc, 0, 0, 0);
    }
    const int col = cb * 16 + la;
    const float byv = by[col];
#pragma unroll
    for (int r = 0; r < 4; ++r) {
      const int row = rowbase + lb * 4 + r;  // C/D: col = lane&15, row = (lane>>4)*4 + r
      out[(size_t)row * VOC + col] = acc[r] + byv;
    }
  }
}

// ---------------- launch ----------------
extern "C" void kernel_launch(void* const* d_in, const int* in_sizes, int n_in,
                              void* d_out, int out_size, void* d_ws, size_t ws_size,
                              hipStream_t stream) {
  const int*   x   = (const int*)d_in[0];
  const float* wih = (const float*)d_in[1];
  const float* whh = (const float*)d_in[2];
  const float* bh  = (const float*)d_in[3];
  const float* why = (const float*)d_in[4];
  const float* by  = (const float*)d_in[5];

  uint32_t* wf = (uint32_t*)d_ws;                          // 512 KB B-fragments of W_hh
  _Float16* wt = (_Float16*)((char*)d_ws + 512 * 1024);    // 256 KB fp16 W_hy^T

  hipLaunchKernelGGL(prep_wfrag, dim3(512), dim3(256), 0, stream, whh, wf);
  hipLaunchKernelGGL(prep_why, dim3(512), dim3(256), 0, stream, why, wt);
  hipLaunchKernelGGL(rnn_phase1, dim3(BATCH), dim3(512), 0, stream,
                     x, wih, (const h8v*)wf, bh, (__half*)d_out);
  hipLaunchKernelGGL(rnn_phase2, dim3((S_LEN * BATCH) / 64), dim3(256), 0, stream,
                     d_out, wt, by);
}

// Round 18
// 1657.404 us; speedup vs baseline: 1.8111x; 1.8111x over previous
//
#include <hip/hip_runtime.h>
#include <hip/hip_fp16.h>
#include <stdint.h>

#define S_LEN 1024
#define BATCH 64
#define HID   512
#define VOC   256

typedef _Float16 h2v __attribute__((ext_vector_type(2)));
typedef _Float16 h8v __attribute__((ext_vector_type(8)));
typedef float    f4v __attribute__((ext_vector_type(4)));
typedef float    f2v __attribute__((ext_vector_type(2)));

__device__ __forceinline__ float fdot2f(uint32_t w, uint32_t h, float c) {
  return __builtin_amdgcn_fdot2(__builtin_bit_cast(h2v, w),
                                __builtin_bit_cast(h2v, h), c, false);
}

// decode 2 fp8 (compile-time-selected word of src) -> packed fp16 pair bits
template <bool WORD>
__device__ __forceinline__ uint32_t fp8_to_h2(uint32_t src) {
  f2v f = __builtin_amdgcn_cvt_pk_f32_fp8(src, WORD);
  auto h = __builtin_amdgcn_cvt_pkrtz(f.x, f.y);  // __fp16 x2, same bits
  return __builtin_bit_cast(uint32_t, h);
}

// ---------------- prep kernels ----------------
// fp16 pairs: wp[k2*HID + n] = (W[2k2][n], W[2k2+1][n])
__global__ void prep_whh(const float* __restrict__ whh, uint32_t* __restrict__ wp) {
  int idx = blockIdx.x * blockDim.x + threadIdx.x;   // 131072
  int k2 = idx >> 9;
  int n  = idx & 511;
  h2v p;
  p.x = (_Float16)whh[(2 * k2) * HID + n];
  p.y = (_Float16)whh[(2 * k2 + 1) * HID + n];
  wp[idx] = __builtin_bit_cast(uint32_t, p);
}

// fp8 e4m3 (HW-encoded) buffer. uint32 idx = (i*128 + nb)*4 + d,
// i = k2-pair [0,128), nb = col-quad [0,128), d in [0,4):
//   k2 = 2i + (d>>1); cols cA = 4nb + (d&1)*2, cB = cA+1
//   word0 = (fp8 W[2k2][cA], fp8 W[2k2+1][cA]); word1 = same for cB
__global__ void prep_wq(const float* __restrict__ whh, uint32_t* __restrict__ wq) {
  int idx = blockIdx.x * blockDim.x + threadIdx.x;   // 65536
  int d  = idx & 3;
  int nb = (idx >> 2) & 127;
  int i  = idx >> 9;
  int k2 = 2 * i + (d >> 1);
  int cA = nb * 4 + (d & 1) * 2;
  int cB = cA + 1;
  int v = __builtin_amdgcn_cvt_pk_fp8_f32(whh[(2 * k2) * HID + cA],
                                          whh[(2 * k2 + 1) * HID + cA], 0, false);
  v = __builtin_amdgcn_cvt_pk_fp8_f32(whh[(2 * k2) * HID + cB],
                                      whh[(2 * k2 + 1) * HID + cB], v, true);
  wq[idx] = (uint32_t)v;
}

// W_hyT[v*HID + k] = fp16 W_hy[k][v]
__global__ void prep_why(const float* __restrict__ why, _Float16* __restrict__ wt) {
  int idx = blockIdx.x * blockDim.x + threadIdx.x;   // 131072
  int v = idx >> 9;
  int k = idx & 511;
  wt[idx] = (_Float16)why[k * VOC + v];
}

// 4-col dot expansion for a fp16-pair weight word quad
#define DOT4(W, H)                                         \
  a0 = fdot2f((W).x, (H), a0); a1 = fdot2f((W).y, (H), a1); \
  a2 = fdot2f((W).z, (H), a2); a3 = fdot2f((W).w, (H), a3);

// ---------------- phase 1: recurrence ----------------
// 64 blocks (one chain), 512 threads = 8 waves, 1 block/CU.
// thread (kq=tid>>7, nb=tid&127): cols n0=nb*4..+3, k2-slices [kq*64,(kq+1)*64).
// Residency: s=0..15 LDS fp16 (128 KB), s=16..31 streamed fp16 (128 KB/step),
//            s=32..63 streamed fp8 (128 KB/step; half the bytes, half the instrs).
__global__ __launch_bounds__(512, 2) void rnn_phase1(
    const int* __restrict__ x, const float* __restrict__ wih,
    const uint32_t* __restrict__ wp, const uint4* __restrict__ wq,
    const float* __restrict__ bh, __half* __restrict__ hbuf) {
  __shared__ __align__(16) uint32_t h2s[HID / 2];  // 1 KB
  __shared__ float part[4][HID];                   // 8 KB
  __shared__ int xtok[S_LEN];                      // 4 KB
  extern __shared__ __align__(16) uint4 lw[];      // 16*512 uint4 = 128 KB

  const int b   = blockIdx.x;
  const int tid = threadIdx.x;
  const int kq  = tid >> 7;
  const int nb  = tid & 127;
  const int n0  = nb * 4;
  const int k2b = kq * 64;

  // ---- LDS-resident slices 0..15
#pragma unroll
  for (int s = 0; s < 16; ++s)
    lw[s * 512 + tid] = *((const uint4*)&wp[(size_t)(k2b + s) * HID + n0]);

  xtok[tid]       = x[b * S_LEN + tid];
  xtok[tid + 512] = x[b * S_LEN + tid + 512];
  if (tid < HID / 2) h2s[tid] = 0u;  // h0 = 0
  const float bh_r = bh[tid];
  // fp8 stream base: i = kq*32+16+j covers k2 = k2b+32+2j, j=0..15
  const uint4* qbase = wq + ((size_t)(kq * 32 + 16) * 128 + nb);
  __syncthreads();

  for (int t = 0; t < S_LEN; ++t) {
    const int tok = xtok[t];
    const float xe = wih[tok * HID + tid];  // early issue; used in reduce

    // streamed fp16 slices 16..31 (loop-invariant addresses, L1/L2-hot)
    uint4 gw[16];
#pragma unroll
    for (int i = 0; i < 16; ++i)
      gw[i] = *((const uint4*)&wp[(size_t)(k2b + 16 + i) * HID + n0]);
    // streamed fp8: 16 x dwordx4, each covers 2 slices (k2b+32+2j, +1)
    uint4 gq[16];
#pragma unroll
    for (int j = 0; j < 16; ++j)
      gq[j] = qbase[(size_t)j * 128];

    float a0 = 0.f, a1 = 0.f, a2 = 0.f, a3 = 0.f;
    const uint4* hq = (const uint4*)&h2s[k2b];  // wave-uniform broadcast reads

    // LDS slices 0..15 (quads 0..3)
#pragma unroll
    for (int q = 0; q < 4; ++q) {
      const uint4 hc = hq[q];
      const uint4 l0 = lw[(q * 4 + 0) * 512 + tid];
      const uint4 l1 = lw[(q * 4 + 1) * 512 + tid];
      const uint4 l2 = lw[(q * 4 + 2) * 512 + tid];
      const uint4 l3 = lw[(q * 4 + 3) * 512 + tid];
      DOT4(l0, hc.x)
      DOT4(l1, hc.y)
      DOT4(l2, hc.z)
      DOT4(l3, hc.w)
    }
    // streamed fp16 slices 16..31 (quads 4..7)
#pragma unroll
    for (int q = 0; q < 4; ++q) {
      const uint4 hc = hq[4 + q];
      DOT4(gw[q * 4 + 0], hc.x)
      DOT4(gw[q * 4 + 1], hc.y)
      DOT4(gw[q * 4 + 2], hc.z)
      DOT4(gw[q * 4 + 3], hc.w)
    }
    // streamed fp8 slices 32..63: gq[j] = {d0,d1} slice even, {d2,d3} slice odd
#pragma unroll
    for (int j = 0; j < 16; ++j) {
      const uint4 v = gq[j];
      const uint32_t he = h2s[k2b + 32 + 2 * j];      // broadcast (uniform addr)
      const uint32_t ho = h2s[k2b + 33 + 2 * j];
      a0 = fdot2f(fp8_to_h2<false>(v.x), he, a0);     // even slice, col n0
      a1 = fdot2f(fp8_to_h2<true >(v.x), he, a1);     // col n1
      a2 = fdot2f(fp8_to_h2<false>(v.y), he, a2);     // col n2
      a3 = fdot2f(fp8_to_h2<true >(v.y), he, a3);     // col n3
      a0 = fdot2f(fp8_to_h2<false>(v.z), ho, a0);     // odd slice
      a1 = fdot2f(fp8_to_h2<true >(v.z), ho, a1);
      a2 = fdot2f(fp8_to_h2<false>(v.w), ho, a2);
      a3 = fdot2f(fp8_to_h2<true >(v.w), ho, a3);
    }

    *((float4*)&part[kq][n0]) = make_float4(a0, a1, a2, a3);
    __syncthreads();  // B1: partials ready; all h2s reads of step t done

    {
      float s = part[0][tid] + part[1][tid] + part[2][tid] + part[3][tid];
      s += xe + bh_r;
      const float e = __builtin_amdgcn_exp2f(s * 2.885390081777927f);  // e^(2s)
      const float h = 1.0f - 2.0f * __builtin_amdgcn_rcpf(e + 1.0f);
      const __half hh = __float2half(h);
      hbuf[(size_t)(t * BATCH + b) * HID + tid] = hh;  // history for phase 2
      ((__half*)h2s)[tid] = hh;                         // recurrent state
    }
    __syncthreads();  // B2: new h visible before next step's reads
  }
}

// ---------------- phase 2: y = h @ W_hy + b_y (fp16 MFMA, in-place over d_out) ----
__global__ __launch_bounds__(256, 1) void rnn_phase2(
    void* __restrict__ out_, const _Float16* __restrict__ wt,
    const float* __restrict__ by) {
  const int tid = threadIdx.x;
  const int w = tid >> 6;
  const int l = tid & 63;
  const int la = l & 15;
  const int lb = l >> 4;
  const int rowbase = blockIdx.x * 64 + w * 16;

  const _Float16* hb = (const _Float16*)out_;
  float* out = (float*)out_;

  h8v a[16];
  const _Float16* arow = hb + (size_t)(rowbase + la) * HID + lb * 8;
#pragma unroll
  for (int kk = 0; kk < 16; ++kk)
    a[kk] = *((const h8v*)(arow + kk * 32));

#pragma unroll 1
  for (int cb = 0; cb < 16; ++cb) {
    f4v acc = {0.f, 0.f, 0.f, 0.f};
    const _Float16* brow = wt + (size_t)(cb * 16 + la) * HID + lb * 8;
#pragma unroll
    for (int kk = 0; kk < 16; ++kk) {
      const h8v bf = *((const h8v*)(brow + kk * 32));
      acc = __builtin_amdgcn_mfma_f32_16x16x32_f16(a[kk], bf, acc, 0, 0, 0);
    }
    const int col = cb * 16 + la;
    const float byv = by[col];
#pragma unroll
    for (int r = 0; r < 4; ++r) {
      const int row = rowbase + lb * 4 + r;  // C/D: col = lane&15, row = (lane>>4)*4 + r
      out[(size_t)row * VOC + col] = acc[r] + byv;
    }
  }
}

// ---------------- launch ----------------
extern "C" void kernel_launch(void* const* d_in, const int* in_sizes, int n_in,
                              void* d_out, int out_size, void* d_ws, size_t ws_size,
                              hipStream_t stream) {
  const int*   x   = (const int*)d_in[0];
  const float* wih = (const float*)d_in[1];
  const float* whh = (const float*)d_in[2];
  const float* bh  = (const float*)d_in[3];
  const float* why = (const float*)d_in[4];
  const float* by  = (const float*)d_in[5];

  uint32_t* wp = (uint32_t*)d_ws;                          // 512 KB fp16 pairs
  _Float16* wt = (_Float16*)((char*)d_ws + 512 * 1024);    // 256 KB W_hy^T
  uint32_t* wq = (uint32_t*)((char*)d_ws + 768 * 1024);    // 256 KB fp8 pairs

  hipLaunchKernelGGL(prep_whh, dim3(512), dim3(256), 0, stream, whh, wp);
  hipLaunchKernelGGL(prep_wq,  dim3(256), dim3(256), 0, stream, whh, wq);
  hipLaunchKernelGGL(prep_why, dim3(512), dim3(256), 0, stream, why, wt);
  hipLaunchKernelGGL(rnn_phase1, dim3(BATCH), dim3(512), 131072, stream,
                     x, wih, wp, (const uint4*)wq, bh, (__half*)d_out);
  hipLaunchKernelGGL(rnn_phase2, dim3((S_LEN * BATCH) / 64), dim3(256), 0, stream,
                     d_out, wt, by);
}